// Round 12
// baseline (330.549 us; speedup 1.0000x reference)
//
#include <hip/hip_runtime.h>

#define BATCH 4096
#define NE 100000
#define NC 4            // chains (b's) per block

typedef __attribute__((ext_vector_type(8))) short bf16x8;
typedef __attribute__((ext_vector_type(4))) float f32x4;

union U4 { uint4 u4; bf16x8 v; };

struct GPtrs {
    const int* h0[5]; const int* h1[5];
    const int* r0[5]; const int* r1[5];
    const int* t0[5]; const int* t1[5];
};

// bf16 truncation pack: word = { hi16(lo) , hi16(hi)<<16 }  (lo -> low half)
__device__ __forceinline__ unsigned trunc2(float lo, float hi){
    return __builtin_amdgcn_perm(__float_as_uint(hi), __float_as_uint(lo), 0x07060302u);
}
__device__ __forceinline__ float bflo(unsigned u){ return __uint_as_float(u << 16); }
__device__ __forceinline__ float bfhi(unsigned u){ return __uint_as_float(u & 0xFFFF0000u); }
__device__ __forceinline__ float bf2f(unsigned short h){ return __uint_as_float(((unsigned)h) << 16); }
__device__ __forceinline__ unsigned addw(unsigned x, unsigned y){
    return trunc2(bflo(x)+bflo(y), bfhi(x)+bfhi(y));
}
__device__ __forceinline__ unsigned mulw(unsigned x, unsigned y){
    return trunc2(bflo(x)*bflo(y), bfhi(x)*bfhi(y));
}
__device__ __forceinline__ float sigm(float x){ return __builtin_amdgcn_rcpf(1.0f + __expf(-x)); }

// ---- prep: E -> ebf (bf16), R -> rbf, W1 -> w1pk (bf16, FRAGMENT order) ----
__global__ __launch_bounds__(256)
void prep_kernel(const float* __restrict__ E, const float* __restrict__ R,
                 const float* __restrict__ W1,
                 unsigned short* __restrict__ ebf, unsigned short* __restrict__ rbf,
                 uint4* __restrict__ w1pk)
{
    const int EC = (NE*64)/8;      // 800000 chunks of 8
    const int RC = (100*64)/8;     // 800
    const int WC = 1024;           // fragment uint4 count
    int stride = gridDim.x * blockDim.x;
    for (int c = blockIdx.x*blockDim.x + threadIdx.x; c < EC + RC + WC; c += stride) {
        if (c < EC + RC) {
            const float* src; unsigned short* dst;
            if (c < EC) { src = E + c*8;      dst = ebf + c*8; }
            else        { src = R + (c-EC)*8; dst = rbf + (c-EC)*8; }
            float4 a = *(const float4*)src;
            float4 b = *(const float4*)(src + 4);
            uint4 o;
            o.x = trunc2(a.x,a.y); o.y = trunc2(a.z,a.w);
            o.z = trunc2(b.x,b.y); o.w = trunc2(b.z,b.w);
            *(uint4*)dst = o;
        } else {
            int c2   = c - (EC + RC);          // 0..1023
            int frag = c2 >> 6;                // jt*4 + ks
            int ln   = c2 & 63;
            int row  = (frag >> 2)*16 + (ln & 15);
            int kp0  = (frag & 3)*16 + 4*(ln >> 4);
            uint4 o;
            o.x = trunc2(W1[(2*kp0    )*64 + row], W1[(2*kp0 + 1)*64 + row]);
            o.y = trunc2(W1[(2*kp0 + 2)*64 + row], W1[(2*kp0 + 3)*64 + row]);
            o.z = trunc2(W1[(2*kp0 + 4)*64 + row], W1[(2*kp0 + 5)*64 + row]);
            o.w = trunc2(W1[(2*kp0 + 6)*64 + row], W1[(2*kp0 + 7)*64 + row]);
            w1pk[c2] = o;
        }
    }
}

// grid = (BATCH/NC, 5). block = 256 = 4 waves; the BLOCK owns (g, b0..b3);
// wave wv owns t-block wv for all 4 chains. 4 independent chains/wave hide
// gather latency (r11 at 2 chains: 61% VALUBusy, ~40% latency stall); total
// VALU work constant. All chain arrays compile-time-indexed (rule #20).
// (256,2): spill-safe cap (tighter bounds spilled 0.5GB in r3/r5/r7).
__global__ __launch_bounds__(256, 2)
void group_kernel(GPtrs gp, const int* __restrict__ items,
                  const float* __restrict__ E,
                  const unsigned short* __restrict__ ebf,
                  const unsigned short* __restrict__ rbf,
                  const uint4* __restrict__ w1pk, const float* __restrict__ W2,
                  float* __restrict__ ws)
{
    const int g    = blockIdx.y;
    const int b0   = blockIdx.x*NC;
    const int tid  = threadIdx.x;
    const int lane = tid & 63;
    const int wv   = tid >> 6;          // 0..3 = t-block

    __shared__ uint4 wlds[1024];           // W1 fragments, 16384 B
    __shared__ float red_log[NC][64];      // attention logits per chain
    __shared__ float red_pv[NC][4][64];    // per-wave partials per chain

    // ---- stage W fragments: straight 16KB copy, 4 uint4 per thread ----
    wlds[tid      ] = w1pk[tid      ];
    wlds[tid + 256] = w1pk[tid + 256];
    wlds[tid + 512] = w1pk[tid + 512];
    wlds[tid + 768] = w1pk[tid + 768];

    const int tcol = lane & 15;          // t within this wave's t-block
    const int q    = lane >> 4;          // k-quarter 0..3
    const int q4   = q * 4;              // k-pair base (for W2)
    const int t_   = wv*16 + tcol;       // triple index for frag gather

    // ---- indices, one per lane, all chains ----
    int vh0[NC], vh1[NC], vr0[NC], vr1[NC], vt0[NC], vt1[NC];
    #pragma unroll
    for (int c = 0; c < NC; ++c) {
        int bb = b0 + c;
        vh0[c] = gp.h0[g][bb*64 + lane];
        vh1[c] = gp.h1[g][bb*64 + lane];
        vr0[c] = gp.r0[g][bb*64 + lane];
        vr1[c] = gp.r1[g][bb*64 + lane];
        vt0[c] = gp.t0[g][bb*64 + lane];
        vt1[c] = gp.t1[g][bb*64 + lane];
    }

    __syncthreads();   // wlds ready

    // ---- init embedding (ddp (g==1): f32 E[items]; else 4-wave mean of E[h0]) ----
    if (g == 1) {
        int bb = b0 + wv;               // 4 waves cover the 4 chains
        ws[((g*3 + 0)*BATCH + bb)*64 + lane] = E[items[bb]*64 + lane];
    } else {
        #pragma unroll
        for (int c = 0; c < NC; ++c) {
            float o0 = 0.f, o1 = 0.f, o2 = 0.f, o3 = 0.f;
            #pragma unroll
            for (int u = 0; u < 16; u += 4) {
                int t = wv*16 + u;
                int r0_ = __shfl(vh0[c], t,   64);
                int r1_ = __shfl(vh0[c], t+1, 64);
                int r2_ = __shfl(vh0[c], t+2, 64);
                int r3_ = __shfl(vh0[c], t+3, 64);
                o0 += bf2f(ebf[r0_*64 + lane]); o1 += bf2f(ebf[r1_*64 + lane]);
                o2 += bf2f(ebf[r2_*64 + lane]); o3 += bf2f(ebf[r3_*64 + lane]);
            }
            red_pv[c][wv][lane] = (o0+o1)+(o2+o3);
        }
        __syncthreads();
        {   // wave wv finalizes chain wv
            int bb = b0 + wv;
            ws[((g*3 + 0)*BATCH + bb)*64 + lane] =
                (red_pv[wv][0][lane]+red_pv[wv][1][lane]+
                 red_pv[wv][2][lane]+red_pv[wv][3][lane]) * (1.0f/64.0f);
        }
    }

    // ---- layer-0 fragments, all chains (persist across layers) ----
    U4 f[NC][4];
    #pragma unroll
    for (int c = 0; c < NC; ++c) {
        int hr = __shfl(vh0[c], t_, 64);
        int pr = __shfl(vr0[c], t_, 64);
        const uint4* hp = (const uint4*)(ebf + hr*64);
        const uint4* pp = (const uint4*)(rbf + pr*64);
        f[c][0].u4 = hp[q];
        f[c][1].u4 = hp[4 + q];
        f[c][2].u4 = pp[q];
        f[c][3].u4 = pp[4 + q];
    }

    #pragma unroll
    for (int L = 0; L < 2; ++L) {
        if (L == 1) {
            // in-place frag update: h += E[h1], p *= R[r1]
            #pragma unroll
            for (int c = 0; c < NC; ++c) {
                int hr = __shfl(vh1[c], t_, 64);
                int pr = __shfl(vr1[c], t_, 64);
                const uint4* hq = (const uint4*)(ebf + hr*64);
                const uint4* pq = (const uint4*)(rbf + pr*64);
                uint4 x0 = hq[q], x1 = hq[4+q], y0 = pq[q], y1 = pq[4+q];
                f[c][0].u4 = make_uint4(addw(f[c][0].u4.x,x0.x), addw(f[c][0].u4.y,x0.y),
                                        addw(f[c][0].u4.z,x0.z), addw(f[c][0].u4.w,x0.w));
                f[c][1].u4 = make_uint4(addw(f[c][1].u4.x,x1.x), addw(f[c][1].u4.y,x1.y),
                                        addw(f[c][1].u4.z,x1.z), addw(f[c][1].u4.w,x1.w));
                f[c][2].u4 = make_uint4(mulw(f[c][2].u4.x,y0.x), mulw(f[c][2].u4.y,y0.y),
                                        mulw(f[c][2].u4.z,y0.z), mulw(f[c][2].u4.w,y0.w));
                f[c][3].u4 = make_uint4(mulw(f[c][3].u4.x,y1.x), mulw(f[c][3].u4.y,y1.y),
                                        mulw(f[c][3].u4.z,y1.z), mulw(f[c][3].u4.w,y1.w));
            }
        }

        // ---- C^T[j][t] via MFMA; each W-frag LDS read feeds NC MFMAs ----
        float pt[NC];
        #pragma unroll
        for (int c = 0; c < NC; ++c) pt[c] = 0.f;
        #pragma unroll
        for (int jt = 0; jt < 4; ++jt) {
            U4 wf0, wf1, wf2, wf3;
            wf0.u4 = wlds[(jt*4 + 0)*64 + lane];
            wf1.u4 = wlds[(jt*4 + 1)*64 + lane];
            wf2.u4 = wlds[(jt*4 + 2)*64 + lane];
            wf3.u4 = wlds[(jt*4 + 3)*64 + lane];
            float4 w2v = *(const float4*)(W2 + jt*16 + q4);
            #pragma unroll
            for (int c = 0; c < NC; ++c) {
                f32x4 acc = {0.f, 0.f, 0.f, 0.f};
                acc = __builtin_amdgcn_mfma_f32_16x16x32_bf16(wf0.v, f[c][0].v, acc, 0,0,0);
                acc = __builtin_amdgcn_mfma_f32_16x16x32_bf16(wf1.v, f[c][1].v, acc, 0,0,0);
                acc = __builtin_amdgcn_mfma_f32_16x16x32_bf16(wf2.v, f[c][2].v, acc, 0,0,0);
                acc = __builtin_amdgcn_mfma_f32_16x16x32_bf16(wf3.v, f[c][3].v, acc, 0,0,0);
                pt[c] += sigm(acc[0])*w2v.x + sigm(acc[1])*w2v.y
                       + sigm(acc[2])*w2v.z + sigm(acc[3])*w2v.w;
            }
        }
        // reduce across k-quarters -> full logits
        #pragma unroll
        for (int c = 0; c < NC; ++c) {
            float p = pt[c];
            p += __shfl_xor(p, 16, 64);
            p += __shfl_xor(p, 32, 64);
            if (lane < 16) red_log[c][wv*16 + lane] = sigm(p);
        }
        __syncthreads();

        // ---- softmax over all 64 t (redundant per wave; t = lane) ----
        float att[NC];
        #pragma unroll
        for (int c = 0; c < NC; ++c) {
            float e = __expf(red_log[c][lane]);
            float d = e;
            #pragma unroll
            for (int m = 32; m > 0; m >>= 1) d += __shfl_xor(d, m, 64);
            att[c] = e * __builtin_amdgcn_rcpf(d);
        }

        // ---- PV: this wave sums its 16 target rows, all chains ----
        #pragma unroll
        for (int c = 0; c < NC; ++c) {
            int vt = (L == 0) ? vt0[c] : vt1[c];
            float o0 = 0.f, o1 = 0.f, o2 = 0.f, o3 = 0.f;
            #pragma unroll
            for (int u = 0; u < 16; u += 4) {
                int t = wv*16 + u;
                int r0_ = __shfl(vt, t,   64);
                int r1_ = __shfl(vt, t+1, 64);
                int r2_ = __shfl(vt, t+2, 64);
                int r3_ = __shfl(vt, t+3, 64);
                float a0_ = __shfl(att[c], t,   64);
                float a1_ = __shfl(att[c], t+1, 64);
                float a2_ = __shfl(att[c], t+2, 64);
                float a3_ = __shfl(att[c], t+3, 64);
                o0 = fmaf(a0_, bf2f(ebf[r0_*64 + lane]), o0);
                o1 = fmaf(a1_, bf2f(ebf[r1_*64 + lane]), o1);
                o2 = fmaf(a2_, bf2f(ebf[r2_*64 + lane]), o2);
                o3 = fmaf(a3_, bf2f(ebf[r3_*64 + lane]), o3);
            }
            red_pv[c][wv][lane] = (o0+o1)+(o2+o3);
        }
        __syncthreads();
        {   // wave wv finalizes chain wv
            int bb = b0 + wv;
            ws[((g*3 + 1 + L)*BATCH + bb)*64 + lane] =
                red_pv[wv][0][lane]+red_pv[wv][1][lane]+
                red_pv[wv][2][lane]+red_pv[wv][3][lane];
        }
        __syncthreads();   // red_pv / red_log reused next layer
    }
}

// score[b] = sigmoid( sum_i (kg[i]+kgp[i])·ddi1[i] + 2·ddi[i]·ddo1[i] )
__launch_bounds__(256, 4)
__global__ void combine_kernel(const float* __restrict__ ws, float* __restrict__ out)
{
    const int tid  = threadIdx.x;
    const int lane = tid & 63;
    const int wv   = tid >> 6;
    const int b    = blockIdx.x*4 + wv;
    float acc = 0.f;
    #pragma unroll
    for (int i = 0; i < 3; ++i) {
        float kg   = ws[((0*3+i)*BATCH + b)*64 + lane];
        float ddi  = ws[((1*3+i)*BATCH + b)*64 + lane];
        float kgp  = ws[((2*3+i)*BATCH + b)*64 + lane];
        float ddi1 = ws[((3*3+i)*BATCH + b)*64 + lane];
        float ddo1 = ws[((4*3+i)*BATCH + b)*64 + lane];
        acc += (kg + kgp)*ddi1 + 2.0f*ddi*ddo1;
    }
    #pragma unroll
    for (int m = 32; m > 0; m >>= 1) acc += __shfl_xor(acc, m, 64);
    if (lane == 0) out[b] = 1.0f/(1.0f + __expf(-acc));
}

extern "C" void kernel_launch(void* const* d_in, const int* in_sizes, int n_in,
                              void* d_out, int out_size, void* d_ws, size_t ws_size,
                              hipStream_t stream)
{
    // input order: 0 items; then 8 prefixes x {h0,h1,r0,r1,t0,t1}:
    // kgi@1, ddp@7, kgp@13, ddo@19(dead), kgi1@25(dead), ddp1@31, kgp1@37(dead), ddo1@43;
    // 49 emb0(unused), 50 emb1(unused), 51 entity_emb, 52 relation_emb, 53 W1, 54 W2
    const int gbase[5] = {1, 7, 13, 31, 43};   // kgi, ddp, kgp, ddp1, ddo1
    GPtrs gp;
    for (int g = 0; g < 5; ++g) {
        gp.h0[g] = (const int*)d_in[gbase[g]+0];
        gp.h1[g] = (const int*)d_in[gbase[g]+1];
        gp.r0[g] = (const int*)d_in[gbase[g]+2];
        gp.r1[g] = (const int*)d_in[gbase[g]+3];
        gp.t0[g] = (const int*)d_in[gbase[g]+4];
        gp.t1[g] = (const int*)d_in[gbase[g]+5];
    }
    const int*   items = (const int*)d_in[0];
    const float* E     = (const float*)d_in[51];
    const float* R     = (const float*)d_in[52];
    const float* W1    = (const float*)d_in[53];
    const float* W2    = (const float*)d_in[54];

    // d_ws layout: [0, 15728640) f32 outputs (5 groups x 3 embs x [B,64]);
    //              then ebf (12.8MB), rbf (12.8KB), w1pk (16KB). Total ~28.6 MB.
    float*          ws  = (float*)d_ws;
    unsigned short* ebf = (unsigned short*)((char*)d_ws + 15728640);
    unsigned short* rbf = (unsigned short*)((char*)d_ws + 15728640 + 12800000);
    uint4*          w1pk= (uint4*)((char*)d_ws + 15728640 + 12800000 + 12800 + 64);

    prep_kernel<<<1024, 256, 0, stream>>>(E, R, W1, ebf, rbf, w1pk);
    dim3 grid(BATCH/NC, 5);
    group_kernel<<<grid, 256, 0, stream>>>(gp, items, E, ebf, rbf, w1pk, W2, ws);
    combine_kernel<<<BATCH/4, 256, 0, stream>>>(ws, (float*)d_out);
}

// Round 13
// 165.603 us; speedup vs baseline: 1.9960x; 1.9960x over previous
//
#include <hip/hip_runtime.h>

#define BATCH 4096
#define NE 100000

typedef __attribute__((ext_vector_type(8))) short bf16x8;
typedef __attribute__((ext_vector_type(4))) float f32x4;

union U4 { uint4 u4; bf16x8 v; };

struct GPtrs {
    const int* h0[5]; const int* h1[5];
    const int* r0[5]; const int* r1[5];
    const int* t0[5]; const int* t1[5];
};

// bf16 truncation pack: word = { hi16(lo) , hi16(hi)<<16 }  (lo -> low half)
__device__ __forceinline__ unsigned trunc2(float lo, float hi){
    return __builtin_amdgcn_perm(__float_as_uint(hi), __float_as_uint(lo), 0x07060302u);
}
__device__ __forceinline__ float bflo(unsigned u){ return __uint_as_float(u << 16); }
__device__ __forceinline__ float bfhi(unsigned u){ return __uint_as_float(u & 0xFFFF0000u); }
__device__ __forceinline__ float bf2f(unsigned short h){ return __uint_as_float(((unsigned)h) << 16); }
__device__ __forceinline__ unsigned addw(unsigned x, unsigned y){
    return trunc2(bflo(x)+bflo(y), bfhi(x)+bfhi(y));
}
__device__ __forceinline__ unsigned mulw(unsigned x, unsigned y){
    return trunc2(bflo(x)*bflo(y), bfhi(x)*bfhi(y));
}
__device__ __forceinline__ float sigm(float x){ return __builtin_amdgcn_rcpf(1.0f + __expf(-x)); }

// ---- prep: E -> ebf (bf16), R -> rbf, W1 -> w1pk (bf16, FRAGMENT order) ----
// w1pk[(jt*4+ks)*64 + lane] = the uint4 (8 bf16) lane `lane` feeds to MFMA(jt,ks).
__global__ __launch_bounds__(256)
void prep_kernel(const float* __restrict__ E, const float* __restrict__ R,
                 const float* __restrict__ W1,
                 unsigned short* __restrict__ ebf, unsigned short* __restrict__ rbf,
                 uint4* __restrict__ w1pk)
{
    const int EC = (NE*64)/8;      // 800000 chunks of 8
    const int RC = (100*64)/8;     // 800
    const int WC = 1024;           // fragment uint4 count
    int stride = gridDim.x * blockDim.x;
    for (int c = blockIdx.x*blockDim.x + threadIdx.x; c < EC + RC + WC; c += stride) {
        if (c < EC + RC) {
            const float* src; unsigned short* dst;
            if (c < EC) { src = E + c*8;      dst = ebf + c*8; }
            else        { src = R + (c-EC)*8; dst = rbf + (c-EC)*8; }
            float4 a = *(const float4*)src;
            float4 b = *(const float4*)(src + 4);
            uint4 o;
            o.x = trunc2(a.x,a.y); o.y = trunc2(a.z,a.w);
            o.z = trunc2(b.x,b.y); o.w = trunc2(b.z,b.w);
            *(uint4*)dst = o;
        } else {
            int c2   = c - (EC + RC);          // 0..1023
            int frag = c2 >> 6;                // jt*4 + ks
            int ln   = c2 & 63;
            int row  = (frag >> 2)*16 + (ln & 15);
            int kp0  = (frag & 3)*16 + 4*(ln >> 4);
            uint4 o;
            o.x = trunc2(W1[(2*kp0    )*64 + row], W1[(2*kp0 + 1)*64 + row]);
            o.y = trunc2(W1[(2*kp0 + 2)*64 + row], W1[(2*kp0 + 3)*64 + row]);
            o.z = trunc2(W1[(2*kp0 + 4)*64 + row], W1[(2*kp0 + 5)*64 + row]);
            o.w = trunc2(W1[(2*kp0 + 6)*64 + row], W1[(2*kp0 + 7)*64 + row]);
            w1pk[c2] = o;
        }
    }
}

// grid = (BATCH/2, 5). block = 256 = 4 waves; BLOCK owns (g, b0, b1);
// wave wv owns t-block wv for BOTH b's (r11 structure = best measured).
// Delta vs r11: red_log/red_pv are LAYER-INDEXED, removing the per-layer
// trailing "buffer reuse" barrier (r11's stall is barrier-lockstep: 4 waves
// drained to the slowest chain at each sync). (256,2): spill-safe cap;
// 4-chain r12 proved +32 VGPR crosses a residency cliff -> keep NC=2.
__global__ __launch_bounds__(256, 2)
void group_kernel(GPtrs gp, const int* __restrict__ items,
                  const float* __restrict__ E,
                  const unsigned short* __restrict__ ebf,
                  const unsigned short* __restrict__ rbf,
                  const uint4* __restrict__ w1pk, const float* __restrict__ W2,
                  float* __restrict__ ws)
{
    const int g    = blockIdx.y;
    const int b0   = blockIdx.x*2;
    const int b1   = b0 + 1;
    const int tid  = threadIdx.x;
    const int lane = tid & 63;
    const int wv   = tid >> 6;          // 0..3 = t-block

    __shared__ uint4 wlds[1024];           // W1 fragments, 16384 B
    __shared__ float red_log[2][2][64];    // [layer][chain][t]
    __shared__ float red_pv[2][2][4][64];  // [layer][chain][wave][d]

    // ---- stage W fragments: straight 16KB copy, 4 uint4 per thread ----
    wlds[tid      ] = w1pk[tid      ];
    wlds[tid + 256] = w1pk[tid + 256];
    wlds[tid + 512] = w1pk[tid + 512];
    wlds[tid + 768] = w1pk[tid + 768];

    const int tcol = lane & 15;          // t within this wave's t-block
    const int q    = lane >> 4;          // k-quarter 0..3
    const int q4   = q * 4;              // k-pair base (for W2)
    const int t_   = wv*16 + tcol;       // triple index for frag gather

    // ---- indices, one per lane, both b's ----
    int vh0A = gp.h0[g][b0*64 + lane], vh0B = gp.h0[g][b1*64 + lane];
    int vh1A = gp.h1[g][b0*64 + lane], vh1B = gp.h1[g][b1*64 + lane];
    int vr0A = gp.r0[g][b0*64 + lane], vr0B = gp.r0[g][b1*64 + lane];
    int vr1A = gp.r1[g][b0*64 + lane], vr1B = gp.r1[g][b1*64 + lane];
    int vt0A = gp.t0[g][b0*64 + lane], vt0B = gp.t0[g][b1*64 + lane];
    int vt1A = gp.t1[g][b0*64 + lane], vt1B = gp.t1[g][b1*64 + lane];

    __syncthreads();   // wlds ready

    // ---- init embedding (ddp (g==1): f32 E[items]; else 4-wave mean of E[h0]) ----
    if (g == 1) {
        if (wv == 0) ws[((g*3 + 0)*BATCH + b0)*64 + lane] = E[items[b0]*64 + lane];
        if (wv == 1) ws[((g*3 + 0)*BATCH + b1)*64 + lane] = E[items[b1]*64 + lane];
    } else {
        float a0 = 0.f, a1 = 0.f, a2 = 0.f, a3 = 0.f;
        float c0 = 0.f, c1 = 0.f, c2 = 0.f, c3 = 0.f;
        #pragma unroll
        for (int u = 0; u < 16; u += 4) {
            int t = wv*16 + u;
            int rA0 = __shfl(vh0A, t,   64), rB0 = __shfl(vh0B, t,   64);
            int rA1 = __shfl(vh0A, t+1, 64), rB1 = __shfl(vh0B, t+1, 64);
            int rA2 = __shfl(vh0A, t+2, 64), rB2 = __shfl(vh0B, t+2, 64);
            int rA3 = __shfl(vh0A, t+3, 64), rB3 = __shfl(vh0B, t+3, 64);
            a0 += bf2f(ebf[rA0*64 + lane]); c0 += bf2f(ebf[rB0*64 + lane]);
            a1 += bf2f(ebf[rA1*64 + lane]); c1 += bf2f(ebf[rB1*64 + lane]);
            a2 += bf2f(ebf[rA2*64 + lane]); c2 += bf2f(ebf[rB2*64 + lane]);
            a3 += bf2f(ebf[rA3*64 + lane]); c3 += bf2f(ebf[rB3*64 + lane]);
        }
        red_pv[0][0][wv][lane] = (a0+a1)+(a2+a3);
        red_pv[0][1][wv][lane] = (c0+c1)+(c2+c3);
        __syncthreads();
        if (wv < 2) {
            int bb = (wv == 0) ? b0 : b1;
            ws[((g*3 + 0)*BATCH + bb)*64 + lane] =
                (red_pv[0][wv][0][lane]+red_pv[0][wv][1][lane]+
                 red_pv[0][wv][2][lane]+red_pv[0][wv][3][lane]) * (1.0f/64.0f);
        }
    }

    // ---- layer-0 fragments, both b's (persist across layers) ----
    U4 fA0, fA1, fA2, fA3, fB0, fB1, fB2, fB3;
    {
        int hrA = __shfl(vh0A, t_, 64), hrB = __shfl(vh0B, t_, 64);
        int prA = __shfl(vr0A, t_, 64), prB = __shfl(vr0B, t_, 64);
        const uint4* hpA = (const uint4*)(ebf + hrA*64);
        const uint4* hpB = (const uint4*)(ebf + hrB*64);
        const uint4* ppA = (const uint4*)(rbf + prA*64);
        const uint4* ppB = (const uint4*)(rbf + prB*64);
        fA0.u4 = hpA[q];     fB0.u4 = hpB[q];
        fA1.u4 = hpA[4 + q]; fB1.u4 = hpB[4 + q];
        fA2.u4 = ppA[q];     fB2.u4 = ppB[q];
        fA3.u4 = ppA[4 + q]; fB3.u4 = ppB[4 + q];
    }

    #pragma unroll
    for (int L = 0; L < 2; ++L) {
        if (L == 1) {
            // in-place frag update: h += E[h1], p *= R[r1]
            int hrA = __shfl(vh1A, t_, 64), hrB = __shfl(vh1B, t_, 64);
            int prA = __shfl(vr1A, t_, 64), prB = __shfl(vr1B, t_, 64);
            const uint4* hqA = (const uint4*)(ebf + hrA*64);
            const uint4* hqB = (const uint4*)(ebf + hrB*64);
            const uint4* pqA = (const uint4*)(rbf + prA*64);
            const uint4* pqB = (const uint4*)(rbf + prB*64);
            uint4 xA0 = hqA[q], xA1 = hqA[4+q], yA0 = pqA[q], yA1 = pqA[4+q];
            uint4 xB0 = hqB[q], xB1 = hqB[4+q], yB0 = pqB[q], yB1 = pqB[4+q];
            fA0.u4 = make_uint4(addw(fA0.u4.x,xA0.x), addw(fA0.u4.y,xA0.y),
                                addw(fA0.u4.z,xA0.z), addw(fA0.u4.w,xA0.w));
            fB0.u4 = make_uint4(addw(fB0.u4.x,xB0.x), addw(fB0.u4.y,xB0.y),
                                addw(fB0.u4.z,xB0.z), addw(fB0.u4.w,xB0.w));
            fA1.u4 = make_uint4(addw(fA1.u4.x,xA1.x), addw(fA1.u4.y,xA1.y),
                                addw(fA1.u4.z,xA1.z), addw(fA1.u4.w,xA1.w));
            fB1.u4 = make_uint4(addw(fB1.u4.x,xB1.x), addw(fB1.u4.y,xB1.y),
                                addw(fB1.u4.z,xB1.z), addw(fB1.u4.w,xB1.w));
            fA2.u4 = make_uint4(mulw(fA2.u4.x,yA0.x), mulw(fA2.u4.y,yA0.y),
                                mulw(fA2.u4.z,yA0.z), mulw(fA2.u4.w,yA0.w));
            fB2.u4 = make_uint4(mulw(fB2.u4.x,yB0.x), mulw(fB2.u4.y,yB0.y),
                                mulw(fB2.u4.z,yB0.z), mulw(fB2.u4.w,yB0.w));
            fA3.u4 = make_uint4(mulw(fA3.u4.x,yA1.x), mulw(fA3.u4.y,yA1.y),
                                mulw(fA3.u4.z,yA1.z), mulw(fA3.u4.w,yA1.w));
            fB3.u4 = make_uint4(mulw(fB3.u4.x,yB1.x), mulw(fB3.u4.y,yB1.y),
                                mulw(fB3.u4.z,yB1.z), mulw(fB3.u4.w,yB1.w));
        }

        // ---- C^T[j][t] via MFMA; each W-frag LDS read feeds both b's ----
        float ptA = 0.f, ptB = 0.f;
        #pragma unroll
        for (int jt = 0; jt < 4; ++jt) {
            U4 wf0, wf1, wf2, wf3;
            wf0.u4 = wlds[(jt*4 + 0)*64 + lane];
            wf1.u4 = wlds[(jt*4 + 1)*64 + lane];
            wf2.u4 = wlds[(jt*4 + 2)*64 + lane];
            wf3.u4 = wlds[(jt*4 + 3)*64 + lane];
            f32x4 accA = {0.f, 0.f, 0.f, 0.f};
            f32x4 accB = {0.f, 0.f, 0.f, 0.f};
            accA = __builtin_amdgcn_mfma_f32_16x16x32_bf16(wf0.v, fA0.v, accA, 0,0,0);
            accB = __builtin_amdgcn_mfma_f32_16x16x32_bf16(wf0.v, fB0.v, accB, 0,0,0);
            accA = __builtin_amdgcn_mfma_f32_16x16x32_bf16(wf1.v, fA1.v, accA, 0,0,0);
            accB = __builtin_amdgcn_mfma_f32_16x16x32_bf16(wf1.v, fB1.v, accB, 0,0,0);
            accA = __builtin_amdgcn_mfma_f32_16x16x32_bf16(wf2.v, fA2.v, accA, 0,0,0);
            accB = __builtin_amdgcn_mfma_f32_16x16x32_bf16(wf2.v, fB2.v, accB, 0,0,0);
            accA = __builtin_amdgcn_mfma_f32_16x16x32_bf16(wf3.v, fA3.v, accA, 0,0,0);
            accB = __builtin_amdgcn_mfma_f32_16x16x32_bf16(wf3.v, fB3.v, accB, 0,0,0);
            float4 w2v = *(const float4*)(W2 + jt*16 + q4);
            ptA += sigm(accA[0])*w2v.x + sigm(accA[1])*w2v.y
                 + sigm(accA[2])*w2v.z + sigm(accA[3])*w2v.w;
            ptB += sigm(accB[0])*w2v.x + sigm(accB[1])*w2v.y
                 + sigm(accB[2])*w2v.z + sigm(accB[3])*w2v.w;
        }
        // reduce across k-quarters -> full logits
        ptA += __shfl_xor(ptA, 16, 64); ptB += __shfl_xor(ptB, 16, 64);
        ptA += __shfl_xor(ptA, 32, 64); ptB += __shfl_xor(ptB, 32, 64);
        if (lane < 16) {
            red_log[L][0][wv*16 + lane] = sigm(ptA);
            red_log[L][1][wv*16 + lane] = sigm(ptB);
        }
        __syncthreads();

        // ---- softmax over all 64 t (redundant per wave; t = lane) ----
        float eA = __expf(red_log[L][0][lane]);
        float eB = __expf(red_log[L][1][lane]);
        float dA = eA, dB = eB;
        #pragma unroll
        for (int m = 32; m > 0; m >>= 1) {
            dA += __shfl_xor(dA, m, 64);
            dB += __shfl_xor(dB, m, 64);
        }
        float attA = eA * __builtin_amdgcn_rcpf(dA);
        float attB = eB * __builtin_amdgcn_rcpf(dB);

        // ---- PV: this wave sums its 16 target rows, both b's ----
        int vtA = (L == 0) ? vt0A : vt1A;
        int vtB = (L == 0) ? vt0B : vt1B;
        float oA0 = 0.f, oA1 = 0.f, oA2 = 0.f, oA3 = 0.f;
        float oB0 = 0.f, oB1 = 0.f, oB2 = 0.f, oB3 = 0.f;
        #pragma unroll
        for (int u = 0; u < 16; u += 4) {
            int t = wv*16 + u;
            int rA0 = __shfl(vtA, t,   64), rB0 = __shfl(vtB, t,   64);
            int rA1 = __shfl(vtA, t+1, 64), rB1 = __shfl(vtB, t+1, 64);
            int rA2 = __shfl(vtA, t+2, 64), rB2 = __shfl(vtB, t+2, 64);
            int rA3 = __shfl(vtA, t+3, 64), rB3 = __shfl(vtB, t+3, 64);
            float aA0 = __shfl(attA, t,   64), aB0 = __shfl(attB, t,   64);
            float aA1 = __shfl(attA, t+1, 64), aB1 = __shfl(attB, t+1, 64);
            float aA2 = __shfl(attA, t+2, 64), aB2 = __shfl(attB, t+2, 64);
            float aA3 = __shfl(attA, t+3, 64), aB3 = __shfl(attB, t+3, 64);
            oA0 = fmaf(aA0, bf2f(ebf[rA0*64 + lane]), oA0);
            oB0 = fmaf(aB0, bf2f(ebf[rB0*64 + lane]), oB0);
            oA1 = fmaf(aA1, bf2f(ebf[rA1*64 + lane]), oA1);
            oB1 = fmaf(aB1, bf2f(ebf[rB1*64 + lane]), oB1);
            oA2 = fmaf(aA2, bf2f(ebf[rA2*64 + lane]), oA2);
            oB2 = fmaf(aB2, bf2f(ebf[rB2*64 + lane]), oB2);
            oA3 = fmaf(aA3, bf2f(ebf[rA3*64 + lane]), oA3);
            oB3 = fmaf(aB3, bf2f(ebf[rB3*64 + lane]), oB3);
        }
        red_pv[L][0][wv][lane] = (oA0+oA1)+(oA2+oA3);
        red_pv[L][1][wv][lane] = (oB0+oB1)+(oB2+oB3);
        __syncthreads();
        if (wv < 2) {
            int bb = (wv == 0) ? b0 : b1;
            ws[((g*3 + 1 + L)*BATCH + bb)*64 + lane] =
                red_pv[L][wv][0][lane]+red_pv[L][wv][1][lane]+
                red_pv[L][wv][2][lane]+red_pv[L][wv][3][lane];
        }
        // no trailing barrier: layer L+1 uses red_*[L+1] (disjoint), and any
        // wave's next write is fenced behind a barrier the readers must reach.
    }
}

// score[b] = sigmoid( sum_i (kg[i]+kgp[i])·ddi1[i] + 2·ddi[i]·ddo1[i] )
__launch_bounds__(256, 4)
__global__ void combine_kernel(const float* __restrict__ ws, float* __restrict__ out)
{
    const int tid  = threadIdx.x;
    const int lane = tid & 63;
    const int wv   = tid >> 6;
    const int b    = blockIdx.x*4 + wv;
    float acc = 0.f;
    #pragma unroll
    for (int i = 0; i < 3; ++i) {
        float kg   = ws[((0*3+i)*BATCH + b)*64 + lane];
        float ddi  = ws[((1*3+i)*BATCH + b)*64 + lane];
        float kgp  = ws[((2*3+i)*BATCH + b)*64 + lane];
        float ddi1 = ws[((3*3+i)*BATCH + b)*64 + lane];
        float ddo1 = ws[((4*3+i)*BATCH + b)*64 + lane];
        acc += (kg + kgp)*ddi1 + 2.0f*ddi*ddo1;
    }
    #pragma unroll
    for (int m = 32; m > 0; m >>= 1) acc += __shfl_xor(acc, m, 64);
    if (lane == 0) out[b] = 1.0f/(1.0f + __expf(-acc));
}

extern "C" void kernel_launch(void* const* d_in, const int* in_sizes, int n_in,
                              void* d_out, int out_size, void* d_ws, size_t ws_size,
                              hipStream_t stream)
{
    // input order: 0 items; then 8 prefixes x {h0,h1,r0,r1,t0,t1}:
    // kgi@1, ddp@7, kgp@13, ddo@19(dead), kgi1@25(dead), ddp1@31, kgp1@37(dead), ddo1@43;
    // 49 emb0(unused), 50 emb1(unused), 51 entity_emb, 52 relation_emb, 53 W1, 54 W2
    const int gbase[5] = {1, 7, 13, 31, 43};   // kgi, ddp, kgp, ddp1, ddo1
    GPtrs gp;
    for (int g = 0; g < 5; ++g) {
        gp.h0[g] = (const int*)d_in[gbase[g]+0];
        gp.h1[g] = (const int*)d_in[gbase[g]+1];
        gp.r0[g] = (const int*)d_in[gbase[g]+2];
        gp.r1[g] = (const int*)d_in[gbase[g]+3];
        gp.t0[g] = (const int*)d_in[gbase[g]+4];
        gp.t1[g] = (const int*)d_in[gbase[g]+5];
    }
    const int*   items = (const int*)d_in[0];
    const float* E     = (const float*)d_in[51];
    const float* R     = (const float*)d_in[52];
    const float* W1    = (const float*)d_in[53];
    const float* W2    = (const float*)d_in[54];

    // d_ws layout: [0, 15728640) f32 outputs (5 groups x 3 embs x [B,64]);
    //              then ebf (12.8MB), rbf (12.8KB), w1pk (16KB). Total ~28.6 MB.
    float*          ws  = (float*)d_ws;
    unsigned short* ebf = (unsigned short*)((char*)d_ws + 15728640);
    unsigned short* rbf = (unsigned short*)((char*)d_ws + 15728640 + 12800000);
    uint4*          w1pk= (uint4*)((char*)d_ws + 15728640 + 12800000 + 12800 + 64);

    prep_kernel<<<1024, 256, 0, stream>>>(E, R, W1, ebf, rbf, w1pk);
    dim3 grid(BATCH/2, 5);
    group_kernel<<<grid, 256, 0, stream>>>(gp, items, E, ebf, rbf, w1pk, W2, ws);
    combine_kernel<<<BATCH/4, 256, 0, stream>>>(ws, (float*)d_out);
}

// Round 14
// 160.906 us; speedup vs baseline: 2.0543x; 1.0292x over previous
//
#include <hip/hip_runtime.h>

#define BATCH 4096
#define NE 100000
#define LOG2E 1.44269504088896f

typedef __attribute__((ext_vector_type(8))) short bf16x8;
typedef __attribute__((ext_vector_type(4))) float f32x4;

union U4 { uint4 u4; bf16x8 v; };

struct GPtrs {
    const int* h0[5]; const int* h1[5];
    const int* r0[5]; const int* r1[5];
    const int* t0[5]; const int* t1[5];
};

// bf16 truncation pack: word = { hi16(lo) , hi16(hi)<<16 }  (lo -> low half)
__device__ __forceinline__ unsigned trunc2(float lo, float hi){
    return __builtin_amdgcn_perm(__float_as_uint(hi), __float_as_uint(lo), 0x07060302u);
}
__device__ __forceinline__ float bflo(unsigned u){ return __uint_as_float(u << 16); }
__device__ __forceinline__ float bfhi(unsigned u){ return __uint_as_float(u & 0xFFFF0000u); }
__device__ __forceinline__ unsigned addw(unsigned x, unsigned y){
    return trunc2(bflo(x)+bflo(y), bfhi(x)+bfhi(y));
}
__device__ __forceinline__ unsigned mulw(unsigned x, unsigned y){
    return trunc2(bflo(x)*bflo(y), bfhi(x)*bfhi(y));
}
__device__ __forceinline__ float sigm(float x){ return __builtin_amdgcn_rcpf(1.0f + __expf(-x)); }
// sigmoid with log2-domain input (W1 pre-scaled by log2e): 1/(1+2^-y)
__device__ __forceinline__ float sigm2(float y){
    return __builtin_amdgcn_rcpf(1.0f + exp2f(-y));
}

// ---- prep: E -> ebf (bf16), R -> rbf, W1*log2e -> w1pk (bf16, FRAGMENT order) ----
__global__ __launch_bounds__(256)
void prep_kernel(const float* __restrict__ E, const float* __restrict__ R,
                 const float* __restrict__ W1,
                 unsigned short* __restrict__ ebf, unsigned short* __restrict__ rbf,
                 uint4* __restrict__ w1pk)
{
    const int EC = (NE*64)/8;      // 800000 chunks of 8
    const int RC = (100*64)/8;     // 800
    const int WC = 1024;           // fragment uint4 count
    int stride = gridDim.x * blockDim.x;
    for (int c = blockIdx.x*blockDim.x + threadIdx.x; c < EC + RC + WC; c += stride) {
        if (c < EC + RC) {
            const float* src; unsigned short* dst;
            if (c < EC) { src = E + c*8;      dst = ebf + c*8; }
            else        { src = R + (c-EC)*8; dst = rbf + (c-EC)*8; }
            float4 a = *(const float4*)src;
            float4 b = *(const float4*)(src + 4);
            uint4 o;
            o.x = trunc2(a.x,a.y); o.y = trunc2(a.z,a.w);
            o.z = trunc2(b.x,b.y); o.w = trunc2(b.z,b.w);
            *(uint4*)dst = o;
        } else {
            int c2   = c - (EC + RC);          // 0..1023
            int frag = c2 >> 6;                // jt*4 + ks
            int ln   = c2 & 63;
            int row  = (frag >> 2)*16 + (ln & 15);
            int kp0  = (frag & 3)*16 + 4*(ln >> 4);
            uint4 o;
            o.x = trunc2(W1[(2*kp0    )*64 + row]*LOG2E, W1[(2*kp0 + 1)*64 + row]*LOG2E);
            o.y = trunc2(W1[(2*kp0 + 2)*64 + row]*LOG2E, W1[(2*kp0 + 3)*64 + row]*LOG2E);
            o.z = trunc2(W1[(2*kp0 + 4)*64 + row]*LOG2E, W1[(2*kp0 + 5)*64 + row]*LOG2E);
            o.w = trunc2(W1[(2*kp0 + 6)*64 + row]*LOG2E, W1[(2*kp0 + 7)*64 + row]*LOG2E);
            w1pk[c2] = o;
        }
    }
}

// grid = (BATCH/2, 5). block = 256 = 4 waves; BLOCK owns (g, b0, b1);
// wave wv owns t-block wv for BOTH b's (r11/r13 structure = best measured).
// Delta vs r13: init & PV gathers process TWO rows per iteration (dword
// loads; lanes 0-31 = even t, 32-63 = odd t) -> half the loads/shfls/addr
// VALU; inner sigmoids run in log2 domain (W1 pre-scaled) -> 1 fewer VALU
// each. (256,2): spill-safe; NC=2 (r12's NC=4 hit a residency cliff).
__global__ __launch_bounds__(256, 2)
void group_kernel(GPtrs gp, const int* __restrict__ items,
                  const float* __restrict__ E,
                  const unsigned short* __restrict__ ebf,
                  const unsigned short* __restrict__ rbf,
                  const uint4* __restrict__ w1pk, const float* __restrict__ W2,
                  float* __restrict__ ws)
{
    const int g    = blockIdx.y;
    const int b0   = blockIdx.x*2;
    const int b1   = b0 + 1;
    const int tid  = threadIdx.x;
    const int lane = tid & 63;
    const int wv   = tid >> 6;          // 0..3 = t-block

    __shared__ uint4 wlds[1024];           // W1 fragments, 16384 B
    __shared__ float red_log[2][2][64];    // [layer][chain][t]
    __shared__ float red_pv[2][2][4][64];  // [layer][chain][wave][d]

    // ---- stage W fragments: straight 16KB copy, 4 uint4 per thread ----
    wlds[tid      ] = w1pk[tid      ];
    wlds[tid + 256] = w1pk[tid + 256];
    wlds[tid + 512] = w1pk[tid + 512];
    wlds[tid + 768] = w1pk[tid + 768];

    const int tcol = lane & 15;          // t within this wave's t-block
    const int q    = lane >> 4;          // k-quarter 0..3
    const int q4   = q * 4;              // k-pair base (for W2)
    const int t_   = wv*16 + tcol;       // triple index for frag gather
    const int bt   = wv*16 + (lane>>5);  // pair-gather base t (half-lane split)
    const int col  = lane & 31;          // dword column within a row
    const unsigned* e32 = (const unsigned*)ebf;

    // ---- indices, one per lane, both b's ----
    int vh0A = gp.h0[g][b0*64 + lane], vh0B = gp.h0[g][b1*64 + lane];
    int vh1A = gp.h1[g][b0*64 + lane], vh1B = gp.h1[g][b1*64 + lane];
    int vr0A = gp.r0[g][b0*64 + lane], vr0B = gp.r0[g][b1*64 + lane];
    int vr1A = gp.r1[g][b0*64 + lane], vr1B = gp.r1[g][b1*64 + lane];
    int vt0A = gp.t0[g][b0*64 + lane], vt0B = gp.t0[g][b1*64 + lane];
    int vt1A = gp.t1[g][b0*64 + lane], vt1B = gp.t1[g][b1*64 + lane];

    __syncthreads();   // wlds ready

    // ---- init embedding (ddp (g==1): f32 E[items]; else 4-wave mean of E[h0]) ----
    if (g == 1) {
        if (wv == 0) ws[((g*3 + 0)*BATCH + b0)*64 + lane] = E[items[b0]*64 + lane];
        if (wv == 1) ws[((g*3 + 0)*BATCH + b1)*64 + lane] = E[items[b1]*64 + lane];
    } else {
        float aL0=0.f,aH0=0.f,aL1=0.f,aH1=0.f;
        float cL0=0.f,cH0=0.f,cL1=0.f,cH1=0.f;
        #pragma unroll
        for (int u = 0; u < 8; ++u) {
            int tt = bt + 2*u;
            int rA = __shfl(vh0A, tt, 64);
            int rB = __shfl(vh0B, tt, 64);
            unsigned wa = e32[rA*32 + col];
            unsigned wb = e32[rB*32 + col];
            if (u & 1) { aL1 += bflo(wa); aH1 += bfhi(wa); cL1 += bflo(wb); cH1 += bfhi(wb); }
            else       { aL0 += bflo(wa); aH0 += bfhi(wa); cL0 += bflo(wb); cH0 += bfhi(wb); }
        }
        float aL = aL0+aL1, aH = aH0+aH1, cL = cL0+cL1, cH = cH0+cH1;
        aL += __shfl_xor(aL, 32, 64); aH += __shfl_xor(aH, 32, 64);
        cL += __shfl_xor(cL, 32, 64); cH += __shfl_xor(cH, 32, 64);
        if (lane < 32) {
            ((float2*)red_pv[0][0][wv])[lane] = make_float2(aL, aH);
            ((float2*)red_pv[0][1][wv])[lane] = make_float2(cL, cH);
        }
        __syncthreads();
        if (wv < 2) {
            int bb = (wv == 0) ? b0 : b1;
            ws[((g*3 + 0)*BATCH + bb)*64 + lane] =
                (red_pv[0][wv][0][lane]+red_pv[0][wv][1][lane]+
                 red_pv[0][wv][2][lane]+red_pv[0][wv][3][lane]) * (1.0f/64.0f);
        }
    }

    // ---- layer-0 fragments, both b's (persist across layers) ----
    U4 fA0, fA1, fA2, fA3, fB0, fB1, fB2, fB3;
    {
        int hrA = __shfl(vh0A, t_, 64), hrB = __shfl(vh0B, t_, 64);
        int prA = __shfl(vr0A, t_, 64), prB = __shfl(vr0B, t_, 64);
        const uint4* hpA = (const uint4*)(ebf + hrA*64);
        const uint4* hpB = (const uint4*)(ebf + hrB*64);
        const uint4* ppA = (const uint4*)(rbf + prA*64);
        const uint4* ppB = (const uint4*)(rbf + prB*64);
        fA0.u4 = hpA[q];     fB0.u4 = hpB[q];
        fA1.u4 = hpA[4 + q]; fB1.u4 = hpB[4 + q];
        fA2.u4 = ppA[q];     fB2.u4 = ppB[q];
        fA3.u4 = ppA[4 + q]; fB3.u4 = ppB[4 + q];
    }

    #pragma unroll
    for (int L = 0; L < 2; ++L) {
        if (L == 1) {
            // in-place frag update: h += E[h1], p *= R[r1]
            int hrA = __shfl(vh1A, t_, 64), hrB = __shfl(vh1B, t_, 64);
            int prA = __shfl(vr1A, t_, 64), prB = __shfl(vr1B, t_, 64);
            const uint4* hqA = (const uint4*)(ebf + hrA*64);
            const uint4* hqB = (const uint4*)(ebf + hrB*64);
            const uint4* pqA = (const uint4*)(rbf + prA*64);
            const uint4* pqB = (const uint4*)(rbf + prB*64);
            uint4 xA0 = hqA[q], xA1 = hqA[4+q], yA0 = pqA[q], yA1 = pqA[4+q];
            uint4 xB0 = hqB[q], xB1 = hqB[4+q], yB0 = pqB[q], yB1 = pqB[4+q];
            fA0.u4 = make_uint4(addw(fA0.u4.x,xA0.x), addw(fA0.u4.y,xA0.y),
                                addw(fA0.u4.z,xA0.z), addw(fA0.u4.w,xA0.w));
            fB0.u4 = make_uint4(addw(fB0.u4.x,xB0.x), addw(fB0.u4.y,xB0.y),
                                addw(fB0.u4.z,xB0.z), addw(fB0.u4.w,xB0.w));
            fA1.u4 = make_uint4(addw(fA1.u4.x,xA1.x), addw(fA1.u4.y,xA1.y),
                                addw(fA1.u4.z,xA1.z), addw(fA1.u4.w,xA1.w));
            fB1.u4 = make_uint4(addw(fB1.u4.x,xB1.x), addw(fB1.u4.y,xB1.y),
                                addw(fB1.u4.z,xB1.z), addw(fB1.u4.w,xB1.w));
            fA2.u4 = make_uint4(mulw(fA2.u4.x,yA0.x), mulw(fA2.u4.y,yA0.y),
                                mulw(fA2.u4.z,yA0.z), mulw(fA2.u4.w,yA0.w));
            fB2.u4 = make_uint4(mulw(fB2.u4.x,yB0.x), mulw(fB2.u4.y,yB0.y),
                                mulw(fB2.u4.z,yB0.z), mulw(fB2.u4.w,yB0.w));
            fA3.u4 = make_uint4(mulw(fA3.u4.x,yA1.x), mulw(fA3.u4.y,yA1.y),
                                mulw(fA3.u4.z,yA1.z), mulw(fA3.u4.w,yA1.w));
            fB3.u4 = make_uint4(mulw(fB3.u4.x,yB1.x), mulw(fB3.u4.y,yB1.y),
                                mulw(fB3.u4.z,yB1.z), mulw(fB3.u4.w,yB1.w));
        }

        // ---- C^T[j][t] via MFMA; each W-frag LDS read feeds both b's ----
        // W1 is log2e-pre-scaled: sigmoid = rcp(1 + exp2(-acc)).
        float ptA = 0.f, ptB = 0.f;
        #pragma unroll
        for (int jt = 0; jt < 4; ++jt) {
            U4 wf0, wf1, wf2, wf3;
            wf0.u4 = wlds[(jt*4 + 0)*64 + lane];
            wf1.u4 = wlds[(jt*4 + 1)*64 + lane];
            wf2.u4 = wlds[(jt*4 + 2)*64 + lane];
            wf3.u4 = wlds[(jt*4 + 3)*64 + lane];
            f32x4 accA = {0.f, 0.f, 0.f, 0.f};
            f32x4 accB = {0.f, 0.f, 0.f, 0.f};
            accA = __builtin_amdgcn_mfma_f32_16x16x32_bf16(wf0.v, fA0.v, accA, 0,0,0);
            accB = __builtin_amdgcn_mfma_f32_16x16x32_bf16(wf0.v, fB0.v, accB, 0,0,0);
            accA = __builtin_amdgcn_mfma_f32_16x16x32_bf16(wf1.v, fA1.v, accA, 0,0,0);
            accB = __builtin_amdgcn_mfma_f32_16x16x32_bf16(wf1.v, fB1.v, accB, 0,0,0);
            accA = __builtin_amdgcn_mfma_f32_16x16x32_bf16(wf2.v, fA2.v, accA, 0,0,0);
            accB = __builtin_amdgcn_mfma_f32_16x16x32_bf16(wf2.v, fB2.v, accB, 0,0,0);
            accA = __builtin_amdgcn_mfma_f32_16x16x32_bf16(wf3.v, fA3.v, accA, 0,0,0);
            accB = __builtin_amdgcn_mfma_f32_16x16x32_bf16(wf3.v, fB3.v, accB, 0,0,0);
            float4 w2v = *(const float4*)(W2 + jt*16 + q4);
            ptA += sigm2(accA[0])*w2v.x + sigm2(accA[1])*w2v.y
                 + sigm2(accA[2])*w2v.z + sigm2(accA[3])*w2v.w;
            ptB += sigm2(accB[0])*w2v.x + sigm2(accB[1])*w2v.y
                 + sigm2(accB[2])*w2v.z + sigm2(accB[3])*w2v.w;
        }
        // reduce across k-quarters -> full logits
        ptA += __shfl_xor(ptA, 16, 64); ptB += __shfl_xor(ptB, 16, 64);
        ptA += __shfl_xor(ptA, 32, 64); ptB += __shfl_xor(ptB, 32, 64);
        if (lane < 16) {
            red_log[L][0][wv*16 + lane] = sigm(ptA);
            red_log[L][1][wv*16 + lane] = sigm(ptB);
        }
        __syncthreads();

        // ---- softmax over all 64 t (redundant per wave; t = lane) ----
        float eA = __expf(red_log[L][0][lane]);
        float eB = __expf(red_log[L][1][lane]);
        float dA = eA, dB = eB;
        #pragma unroll
        for (int m = 32; m > 0; m >>= 1) {
            dA += __shfl_xor(dA, m, 64);
            dB += __shfl_xor(dB, m, 64);
        }
        float attA = eA * __builtin_amdgcn_rcpf(dA);
        float attB = eB * __builtin_amdgcn_rcpf(dB);

        // ---- PV: dword-pair gather (2 rows/iter via lane halves) ----
        int vtA = (L == 0) ? vt0A : vt1A;
        int vtB = (L == 0) ? vt0B : vt1B;
        float aL0=0.f,aH0=0.f,aL1=0.f,aH1=0.f;
        float cL0=0.f,cH0=0.f,cL1=0.f,cH1=0.f;
        #pragma unroll
        for (int u = 0; u < 8; ++u) {
            int tt = bt + 2*u;
            int rA = __shfl(vtA, tt, 64);
            float wA = __shfl(attA, tt, 64);
            int rB = __shfl(vtB, tt, 64);
            float wB = __shfl(attB, tt, 64);
            unsigned da = e32[rA*32 + col];
            unsigned db = e32[rB*32 + col];
            if (u & 1) {
                aL1 = fmaf(wA, bflo(da), aL1); aH1 = fmaf(wA, bfhi(da), aH1);
                cL1 = fmaf(wB, bflo(db), cL1); cH1 = fmaf(wB, bfhi(db), cH1);
            } else {
                aL0 = fmaf(wA, bflo(da), aL0); aH0 = fmaf(wA, bfhi(da), aH0);
                cL0 = fmaf(wB, bflo(db), cL0); cH0 = fmaf(wB, bfhi(db), cH0);
            }
        }
        float aL = aL0+aL1, aH = aH0+aH1, cL = cL0+cL1, cH = cH0+cH1;
        aL += __shfl_xor(aL, 32, 64); aH += __shfl_xor(aH, 32, 64);
        cL += __shfl_xor(cL, 32, 64); cH += __shfl_xor(cH, 32, 64);
        if (lane < 32) {
            ((float2*)red_pv[L][0][wv])[lane] = make_float2(aL, aH);
            ((float2*)red_pv[L][1][wv])[lane] = make_float2(cL, cH);
        }
        __syncthreads();
        if (wv < 2) {
            int bb = (wv == 0) ? b0 : b1;
            ws[((g*3 + 1 + L)*BATCH + bb)*64 + lane] =
                red_pv[L][wv][0][lane]+red_pv[L][wv][1][lane]+
                red_pv[L][wv][2][lane]+red_pv[L][wv][3][lane];
        }
        // no trailing barrier: layer L+1 uses red_*[L+1] (disjoint).
    }
}

// score[b] = sigmoid( sum_i (kg[i]+kgp[i])·ddi1[i] + 2·ddi[i]·ddo1[i] )
__launch_bounds__(256, 4)
__global__ void combine_kernel(const float* __restrict__ ws, float* __restrict__ out)
{
    const int tid  = threadIdx.x;
    const int lane = tid & 63;
    const int wv   = tid >> 6;
    const int b    = blockIdx.x*4 + wv;
    float acc = 0.f;
    #pragma unroll
    for (int i = 0; i < 3; ++i) {
        float kg   = ws[((0*3+i)*BATCH + b)*64 + lane];
        float ddi  = ws[((1*3+i)*BATCH + b)*64 + lane];
        float kgp  = ws[((2*3+i)*BATCH + b)*64 + lane];
        float ddi1 = ws[((3*3+i)*BATCH + b)*64 + lane];
        float ddo1 = ws[((4*3+i)*BATCH + b)*64 + lane];
        acc += (kg + kgp)*ddi1 + 2.0f*ddi*ddo1;
    }
    #pragma unroll
    for (int m = 32; m > 0; m >>= 1) acc += __shfl_xor(acc, m, 64);
    if (lane == 0) out[b] = 1.0f/(1.0f + __expf(-acc));
}

extern "C" void kernel_launch(void* const* d_in, const int* in_sizes, int n_in,
                              void* d_out, int out_size, void* d_ws, size_t ws_size,
                              hipStream_t stream)
{
    // input order: 0 items; then 8 prefixes x {h0,h1,r0,r1,t0,t1}:
    // kgi@1, ddp@7, kgp@13, ddo@19(dead), kgi1@25(dead), ddp1@31, kgp1@37(dead), ddo1@43;
    // 49 emb0(unused), 50 emb1(unused), 51 entity_emb, 52 relation_emb, 53 W1, 54 W2
    const int gbase[5] = {1, 7, 13, 31, 43};   // kgi, ddp, kgp, ddp1, ddo1
    GPtrs gp;
    for (int g = 0; g < 5; ++g) {
        gp.h0[g] = (const int*)d_in[gbase[g]+0];
        gp.h1[g] = (const int*)d_in[gbase[g]+1];
        gp.r0[g] = (const int*)d_in[gbase[g]+2];
        gp.r1[g] = (const int*)d_in[gbase[g]+3];
        gp.t0[g] = (const int*)d_in[gbase[g]+4];
        gp.t1[g] = (const int*)d_in[gbase[g]+5];
    }
    const int*   items = (const int*)d_in[0];
    const float* E     = (const float*)d_in[51];
    const float* R     = (const float*)d_in[52];
    const float* W1    = (const float*)d_in[53];
    const float* W2    = (const float*)d_in[54];

    // d_ws layout: [0, 15728640) f32 outputs (5 groups x 3 embs x [B,64]);
    //              then ebf (12.8MB), rbf (12.8KB), w1pk (16KB). Total ~28.6 MB.
    float*          ws  = (float*)d_ws;
    unsigned short* ebf = (unsigned short*)((char*)d_ws + 15728640);
    unsigned short* rbf = (unsigned short*)((char*)d_ws + 15728640 + 12800000);
    uint4*          w1pk= (uint4*)((char*)d_ws + 15728640 + 12800000 + 12800 + 64);

    prep_kernel<<<1024, 256, 0, stream>>>(E, R, W1, ebf, rbf, w1pk);
    dim3 grid(BATCH/2, 5);
    group_kernel<<<grid, 256, 0, stream>>>(gp, items, E, ebf, rbf, w1pk, W2, ws);
    combine_kernel<<<BATCH/4, 256, 0, stream>>>(ws, (float*)d_out);
}